// Round 4
// baseline (894.533 us; speedup 1.0000x reference)
//
#include <hip/hip_runtime.h>

// VQ codebook: z_e (16,256,32,32) f32, codebook (8192,256) f32.
// out f32: z_q_st[4194304] | loss[1] | codes[16384].
// n = b*1024+hw; z_flat[n][d] = z_e[b*262144 + d*1024 + hw]
// Reference: dist = fl32(zz - 2*dot), dot = sequential f32 FMA chain d=0..255,
// argmin ties -> lowest index.  (validated bitwise in round 2)
//
// Round-4 strategy: hh-only bf16 MFMA screen (32x32x16), z-rows register-
// stationary, codebook streamed through 64KB LDS ping-pong. Per-row running
// max(dot) -> global atomicMax threshold -> candidate append -> exact rescore.

#define CAP 32

typedef short bf16x8 __attribute__((ext_vector_type(8)));
typedef float f32x16 __attribute__((ext_vector_type(16)));
typedef float f32x4 __attribute__((ext_vector_type(4)));

__device__ __forceinline__ unsigned short f2bf(float f) {
    unsigned u = __float_as_uint(f);
    return (unsigned short)((u + 0x7fffu + ((u >> 16) & 1u)) >> 16);
}
__device__ __forceinline__ float ulpf(float x) {   // 2^(exp(x)-23), x normal positive
    return __uint_as_float((__float_as_uint(x) & 0x7f800000u) - (23u << 23));
}
// monotone float<->uint key (total order matches float order)
__device__ __forceinline__ unsigned fkey(float f) {
    unsigned u = __float_as_uint(f);
    return (u & 0x80000000u) ? ~u : (u | 0x80000000u);
}
__device__ __forceinline__ float funkey(unsigned k) {
    unsigned u = (k & 0x80000000u) ? (k ^ 0x80000000u) : ~k;
    return __uint_as_float(u);
}

// ---- ws byte layout (big path) ----
#define ZN_B      0u          // f32[16384]
#define MRG_B     65536u      // f32[16384]  (acc-domain half margin)
#define CODES_B   131072u     // i32[16384]
#define CNT_B     196608u     // u32[16384]
#define TAU_B     262144u     // u32[16384]  (fkey of row max dot)
#define CANDI_B   327680u     // i32[16384*CAP] = 2 MB
#define ZH_B      4194304u    // bf16[16384][256] = 8 MB
#define CH_B      12582912u   // bf16[8192][256] = 4 MB
#define WS_NEED   16777216u

// ---------------- znorm + margin ----------------
__global__ __launch_bounds__(256)
void znorm_kernel(const float* __restrict__ z, float* __restrict__ zn,
                  float* __restrict__ mrg) {
    int n = blockIdx.x * 256 + threadIdx.x;
    int b = n >> 10, hw = n & 1023;
    const float* zp = z + (size_t)b * 262144 + hw;
    float s = 0.f;
    for (int d = 0; d < 256; ++d) {
        float v = zp[(size_t)d << 10];
        s += v * v;
    }
    zn[n] = s;
    // score-domain margin = 4*ulp(zz) + 2e-4 ; acc(dot)-domain half = /2
    mrg[n] = 2.0f * ulpf(s) + 1.0e-4f;
}

// ---------------- prep: z -> bf16 with transpose ----------------
__global__ __launch_bounds__(256)
void split_z_kernel(const float* __restrict__ z, unsigned short* __restrict__ zh) {
    __shared__ float t[64][65];
    const int b = blockIdx.z, hw0 = blockIdx.x * 64, d0 = blockIdx.y * 64;
    const int c = threadIdx.x & 63, rg = threadIdx.x >> 6;
#pragma unroll
    for (int it = 0; it < 16; ++it) {
        int dl = it * 4 + rg;
        t[dl][c] = z[(size_t)b * 262144 + (size_t)(d0 + dl) * 1024 + hw0 + c];
    }
    __syncthreads();
#pragma unroll
    for (int it = 0; it < 16; ++it) {
        int nl = it * 4 + rg;
        zh[(size_t)(b * 1024 + hw0 + nl) * 256 + d0 + c] = f2bf(t[c][nl]);
    }
}

// ---------------- prep: codebook -> bf16 ----------------
__global__ __launch_bounds__(256)
void split_c_kernel(const float* __restrict__ cb, unsigned short* __restrict__ ch) {
    int gid = blockIdx.x * 256 + threadIdx.x;     // float4 index; 524288 total
    float4 v = ((const float4*)cb)[gid];
    ushort4 hv;
    hv.x = f2bf(v.x); hv.y = f2bf(v.y); hv.z = f2bf(v.z); hv.w = f2bf(v.w);
    ((ushort4*)ch)[gid] = hv;
}

// ---------------- screening GEMM (32x32x16, z stationary) ----------------
// grid 256 blocks x 512 thr (8 waves = 2 rowgroups x 4 code-quarters).
// Block owns 64 z-rows; streams all 8192 codes in 64 tiles of 128.
__global__ __launch_bounds__(512, 2)
void gemm_screen32(const unsigned short* __restrict__ zh,
                   const unsigned short* __restrict__ ch,
                   const float* __restrict__ mrg,
                   unsigned* __restrict__ tau_g, unsigned* __restrict__ cnt,
                   int* __restrict__ cand) {
    __shared__ char buf[65536];   // 128 codes x 512B (xor-slot swizzled)
    const int tid = threadIdx.x;
    const int l = tid & 63;
    const int wv = tid >> 6;
    const int rg = wv >> 2;       // row-group (0..1)
    const int cq = wv & 3;        // code-quarter (0..3)
    const int l5 = l >> 5, l31 = l & 31;
    const int n0 = blockIdx.x * 64;

    // A fragments: 32 z-rows (this rowgroup) x all 256 d, in registers.
    // 32x32x16 A-frag: lane l holds A[row=l&31][k=(l>>5)*8 + 0..7]
    bf16x8 a[16];
    {
        const unsigned short* zrow = zh + (size_t)(n0 + rg * 32 + l31) * 256;
#pragma unroll
        for (int k = 0; k < 16; ++k)
            a[k] = *(const bf16x8*)(zrow + k * 16 + l5 * 8);
    }

    float best[16], tau[16];
#pragma unroll
    for (int r = 0; r < 16; ++r) { best[r] = -3.0e38f; tau[r] = 3.0e38f; }

    // staging registers + prologue stage of tile 0
    uint4 st[8];
#pragma unroll
    for (int j = 0; j < 8; ++j) {
        int c = j * 16 + (tid >> 5);
        int slog = (tid & 31) ^ (c & 31);
        st[j] = *(const uint4*)(ch + (size_t)c * 256 + slog * 8);
    }
#pragma unroll
    for (int j = 0; j < 8; ++j)
        *(uint4*)(buf + j * 8192 + tid * 16) = st[j];
    __syncthreads();

    for (int t = 0; t < 64; ++t) {
        // issue next tile's loads early (hide under MFMA)
        if (t < 63) {
            const int code0 = (t + 1) * 128;
#pragma unroll
            for (int j = 0; j < 8; ++j) {
                int c = j * 16 + (tid >> 5);
                int slog = (tid & 31) ^ (c & 31);
                st[j] = *(const uint4*)(ch + (size_t)(code0 + c) * 256 + slog * 8);
            }
        }
        // compute: 16 d-chunks, 2 independent MFMA chains
        f32x16 accA, accB;
#pragma unroll
        for (int r = 0; r < 16; ++r) { accA[r] = 0.f; accB[r] = 0.f; }
        const int cbyte = (cq * 32 + l31) * 512;
#pragma unroll
        for (int k = 0; k < 16; k += 2) {
            bf16x8 b0 = *(const bf16x8*)(buf + cbyte + (((2 * k + l5) ^ l31) << 4));
            bf16x8 b1 = *(const bf16x8*)(buf + cbyte + (((2 * (k + 1) + l5) ^ l31) << 4));
            accA = __builtin_amdgcn_mfma_f32_32x32x16_bf16(a[k], b0, accA, 0, 0, 0);
            accB = __builtin_amdgcn_mfma_f32_32x32x16_bf16(a[k + 1], b1, accB, 0, 0, 0);
        }
        float s[16];
#pragma unroll
        for (int r = 0; r < 16; ++r) {
            s[r] = accA[r] + accB[r];
            best[r] = fmaxf(best[r], s[r]);
        }
        const bool rf = (t == 0) || ((t & 3) == 3);
        if (rf) {
#pragma unroll
            for (int r = 0; r < 16; ++r) {
                float m = best[r];
#pragma unroll
                for (int msk = 1; msk <= 16; msk <<= 1)
                    m = fmaxf(m, __shfl_xor(m, msk));
                if (l31 == 0) {
                    int n = n0 + rg * 32 + 4 * l5 + (r & 3) + 8 * (r >> 2);
                    atomicMax(&tau_g[n], fkey(m));
                }
            }
        }
        __syncthreads();   // reads of buf done; atomicMax of all waves visible
        if (rf) {
#pragma unroll
            for (int r = 0; r < 16; ++r) {
                int n = n0 + rg * 32 + 4 * l5 + (r & 3) + 8 * (r >> 2);
                tau[r] = funkey(tau_g[n]) - mrg[n];   // stale-low safe
            }
        }
        // candidate appends (rare)
        {
            const int code = t * 128 + cq * 32 + l31;
#pragma unroll
            for (int r = 0; r < 16; ++r) {
                if (s[r] >= tau[r]) {
                    int n = n0 + rg * 32 + 4 * l5 + (r & 3) + 8 * (r >> 2);
                    unsigned slot = atomicAdd(&cnt[n], 1u);
                    if (slot < CAP) cand[n * CAP + slot] = code;
                }
            }
        }
        // write staged tile (vmcnt wait auto-inserted via register dep)
        if (t < 63) {
#pragma unroll
            for (int j = 0; j < 8; ++j)
                *(uint4*)(buf + j * 8192 + tid * 16) = st[j];
        }
        __syncthreads();
    }
}

// ---------------- exact rescore + final argmin ----------------
__global__ __launch_bounds__(256)
void select_kernel(const float* __restrict__ z, const float* __restrict__ cb,
                   const float* __restrict__ zn, const unsigned* __restrict__ cnt,
                   const int* __restrict__ cand_i,
                   int* __restrict__ codes, float* __restrict__ out_codes) {
    __shared__ float zrow_s[4][256];
    const int wv = threadIdx.x >> 6, lane = threadIdx.x & 63;
    const int n = blockIdx.x * 4 + wv;
    const int b = n >> 10, hw = n & 1023;
    const float* zp = z + (size_t)b * 262144 + hw;
#pragma unroll
    for (int t = 0; t < 4; ++t)
        zrow_s[wv][t * 64 + lane] = zp[(size_t)(t * 64 + lane) << 10];
    const float zz = zn[n];
    const unsigned c = cnt[n];
    float bs; int bi;
    if (c > 0 && c <= CAP) {
        int myk = 0x7fffffff; float ss = 3.0e38f;
        if (lane < (int)c) {
            myk = cand_i[n * CAP + lane];
            const float* cr = cb + (size_t)myk * 256;
            float dot = 0.f;
            for (int d4 = 0; d4 < 64; ++d4) {       // exact sequential chain
                float4 cv = ((const float4*)cr)[d4];
                float4 zv = ((const float4*)&zrow_s[wv][0])[d4];
                dot = fmaf(zv.x, cv.x, dot);
                dot = fmaf(zv.y, cv.y, dot);
                dot = fmaf(zv.z, cv.z, dot);
                dot = fmaf(zv.w, cv.w, dot);
            }
            ss = zz - 2.0f * dot;
        }
        bs = ss; bi = myk;
    } else {
        // fallback: exact full scan (overflowed candidate list)
        bs = 3.0e38f; bi = 0x7fffffff;
        for (int j = 0; j < 128; j += 4) {
            const float* c0 = cb + (size_t)((j + 0) * 64 + lane) * 256;
            const float* c1 = cb + (size_t)((j + 1) * 64 + lane) * 256;
            const float* c2 = cb + (size_t)((j + 2) * 64 + lane) * 256;
            const float* c3 = cb + (size_t)((j + 3) * 64 + lane) * 256;
            float dA = 0.f, dB = 0.f, dC = 0.f, dD = 0.f;
            for (int d4 = 0; d4 < 64; ++d4) {
                float4 zv = ((const float4*)&zrow_s[wv][0])[d4];
                float4 v0 = ((const float4*)c0)[d4];
                float4 v1 = ((const float4*)c1)[d4];
                float4 v2 = ((const float4*)c2)[d4];
                float4 v3 = ((const float4*)c3)[d4];
                dA = fmaf(zv.x, v0.x, dA); dA = fmaf(zv.y, v0.y, dA); dA = fmaf(zv.z, v0.z, dA); dA = fmaf(zv.w, v0.w, dA);
                dB = fmaf(zv.x, v1.x, dB); dB = fmaf(zv.y, v1.y, dB); dB = fmaf(zv.z, v1.z, dB); dB = fmaf(zv.w, v1.w, dB);
                dC = fmaf(zv.x, v2.x, dC); dC = fmaf(zv.y, v2.y, dC); dC = fmaf(zv.z, v2.z, dC); dC = fmaf(zv.w, v2.w, dC);
                dD = fmaf(zv.x, v3.x, dD); dD = fmaf(zv.y, v3.y, dD); dD = fmaf(zv.z, v3.z, dD); dD = fmaf(zv.w, v3.w, dD);
            }
            float sA = zz - 2.0f * dA, sB = zz - 2.0f * dB, sC = zz - 2.0f * dC, sD = zz - 2.0f * dD;
            int kA = (j + 0) * 64 + lane, kB = (j + 1) * 64 + lane, kC = (j + 2) * 64 + lane, kD = (j + 3) * 64 + lane;
            if (sA < bs) { bs = sA; bi = kA; }
            if (sB < bs) { bs = sB; bi = kB; }
            if (sC < bs) { bs = sC; bi = kC; }
            if (sD < bs) { bs = sD; bi = kD; }
        }
    }
#pragma unroll
    for (int m = 1; m <= 32; m <<= 1) {
        float ps = __shfl_xor(bs, m);
        int pi = __shfl_xor(bi, m);
        if (ps < bs || (ps == bs && pi < bi)) { bs = ps; bi = pi; }
    }
    if (lane == 0) { codes[n] = bi; out_codes[n] = (float)bi; }
}

// ---------------- finalize: z_q gather + loss ----------------
__global__ __launch_bounds__(256)
void finalize2_kernel(const float* __restrict__ z, const float* __restrict__ cb,
                      const int* __restrict__ codes, float* __restrict__ out) {
    __shared__ int codes_s[64];
    __shared__ float wsum[4];
    const int nbase = blockIdx.x * 64;
    const int tid = threadIdx.x;
    if (tid < 64) codes_s[tid] = codes[nbase + tid];
    __syncthreads();
    const int lane = tid & 63;
    const int w = tid >> 6;
    const int n = nbase + lane;
    const int b = n >> 10, hw = n & 1023;
    const int code = codes_s[lane];
    const float* crow = cb + (size_t)code * 256;
    const float* zrow = z + (size_t)b * 262144 + hw;
    float* orow = out + (size_t)b * 262144 + hw;
    float part = 0.f;
    for (int j = 0; j < 64; ++j) {
        int d = w * 64 + j;
        float cv = crow[d];
        float ze = zrow[(size_t)d * 1024];
        orow[(size_t)d * 1024] = cv;
        float diff = ze - cv;
        part += diff * diff;
    }
#pragma unroll
    for (int off = 32; off > 0; off >>= 1) part += __shfl_down(part, off);
    if (lane == 0) wsum[w] = part;
    __syncthreads();
    if (tid == 0) {
        float t = (wsum[0] + wsum[1] + wsum[2] + wsum[3]) * (1.25f / 4194304.f);
        atomicAdd(out + 4194304, t);
    }
}

// ================= fallback path (round-2 kernels, ws-small case) =================
#define NT 128
#define KT 128
#define DC 64
#define KS 4
#define KRANGE (8192 / KS)
#define PSCORE_OFF 16384
#define PIDX_OFF (16384 + KS * 16384)

__global__ __launch_bounds__(256, 2)
void dist_argmin_kernel(const float* __restrict__ z, const float* __restrict__ cb,
                        const float* __restrict__ zn,
                        float* __restrict__ pscore, int* __restrict__ pidx) {
    __shared__ float zs[DC][NT];
    __shared__ float cs[DC][KT];
    const int tid = threadIdx.x;
    const int tn = tid & 15;
    const int tk = tid >> 4;
    const int n0 = blockIdx.x * NT;
    const int b = n0 >> 10;
    const int hw0 = n0 & 1023;
    const float* zb = z + (size_t)b * 262144 + hw0;
    const int k0base = blockIdx.y * KRANGE;
    float zzr[8];
#pragma unroll
    for (int i = 0; i < 8; ++i) {
        int row = (i < 4) ? (tn * 4 + i) : (64 + tn * 4 + (i - 4));
        zzr[i] = zn[n0 + row];
    }
    float best[8]; int bidx[8];
#pragma unroll
    for (int i = 0; i < 8; ++i) { best[i] = 3.0e38f; bidx[i] = 0; }
    for (int kt = 0; kt < KRANGE / KT; ++kt) {
        const int k0 = k0base + kt * KT;
        float acc[8][8];
#pragma unroll
        for (int i = 0; i < 8; ++i)
#pragma unroll
            for (int j = 0; j < 8; ++j) acc[i][j] = 0.f;
        for (int dc = 0; dc < 256; dc += DC) {
            __syncthreads();
#pragma unroll
            for (int it = 0; it < 8; ++it) {
                int idx = it * 256 + tid;
                int d = idx >> 5, nv = idx & 31;
                float4 v = *(const float4*)(zb + (size_t)(dc + d) * 1024 + nv * 4);
                *(float4*)&zs[d][nv * 4] = v;
            }
#pragma unroll
            for (int it = 0; it < 8; ++it) {
                int idx = it * 256 + tid;
                int k = idx >> 4, dv = idx & 15;
                float4 v = *(const float4*)(cb + (size_t)(k0 + k) * 256 + dc + dv * 4);
                int colv = k ^ ((dv & 7) << 2);
                cs[dv * 4 + 0][colv] = v.x;
                cs[dv * 4 + 1][colv] = v.y;
                cs[dv * 4 + 2][colv] = v.z;
                cs[dv * 4 + 3][colv] = v.w;
            }
            __syncthreads();
#pragma unroll 2
            for (int d = 0; d < DC; ++d) {
                int swz = ((d >> 2) & 7) << 2;
                float4 a0 = *(const float4*)&zs[d][tn * 4];
                float4 a1 = *(const float4*)&zs[d][64 + tn * 4];
                float4 b0 = *(const float4*)&cs[d][(tk * 4) ^ swz];
                float4 b1 = *(const float4*)&cs[d][(64 + tk * 4) ^ swz];
                float av[8] = {a0.x, a0.y, a0.z, a0.w, a1.x, a1.y, a1.z, a1.w};
                float bv[8] = {b0.x, b0.y, b0.z, b0.w, b1.x, b1.y, b1.z, b1.w};
#pragma unroll
                for (int i = 0; i < 8; ++i)
#pragma unroll
                    for (int j = 0; j < 8; ++j)
                        acc[i][j] = fmaf(av[i], bv[j], acc[i][j]);
            }
        }
#pragma unroll
        for (int j = 0; j < 8; ++j) {
            int kloc = (j < 4) ? (tk * 4 + j) : (64 + tk * 4 + (j - 4));
            int kk = k0 + kloc;
#pragma unroll
            for (int i = 0; i < 8; ++i) {
                float s = zzr[i] - 2.0f * acc[i][j];
                if (s < best[i]) { best[i] = s; bidx[i] = kk; }
            }
        }
    }
    __syncthreads();
    float* sredf = &zs[0][0];
    int* sredi = (int*)&cs[0][0];
#pragma unroll
    for (int i = 0; i < 8; ++i) {
        int row = (i < 4) ? (tn * 4 + i) : (64 + tn * 4 + (i - 4));
        sredf[row * 16 + tk] = best[i];
        sredi[row * 16 + tk] = bidx[i];
    }
    __syncthreads();
    if (tid < NT) {
        float bs = sredf[tid * 16];
        int bi = sredi[tid * 16];
#pragma unroll
        for (int t = 1; t < 16; ++t) {
            float s = sredf[tid * 16 + t];
            int ix = sredi[tid * 16 + t];
            if (s < bs || (s == bs && ix < bi)) { bs = s; bi = ix; }
        }
        pscore[blockIdx.y * 16384 + n0 + tid] = bs;
        pidx[blockIdx.y * 16384 + n0 + tid] = bi;
    }
}

__global__ __launch_bounds__(256)
void finalize_kernel(const float* __restrict__ z, const float* __restrict__ cb,
                     const float* __restrict__ pscore, const int* __restrict__ pidx,
                     float* __restrict__ out) {
    __shared__ int codes_s[64];
    __shared__ float wsum[4];
    const int nbase = blockIdx.x * 64;
    const int tid = threadIdx.x;
    if (tid < 64) {
        int n = nbase + tid;
        float bs = pscore[n];
        int bi = pidx[n];
#pragma unroll
        for (int p = 1; p < KS; ++p) {
            float s = pscore[p * 16384 + n];
            int ix = pidx[p * 16384 + n];
            if (s < bs || (s == bs && ix < bi)) { bs = s; bi = ix; }
        }
        codes_s[tid] = bi;
        out[4194305 + n] = (float)bi;
    }
    __syncthreads();
    const int lane = tid & 63;
    const int w = tid >> 6;
    const int n = nbase + lane;
    const int b = n >> 10, hw = n & 1023;
    const int code = codes_s[lane];
    const float* crow = cb + (size_t)code * 256;
    const float* zrow = z + (size_t)b * 262144 + hw;
    float* orow = out + (size_t)b * 262144 + hw;
    float part = 0.f;
    for (int j = 0; j < 64; ++j) {
        int d = w * 64 + j;
        float cv = crow[d];
        float ze = zrow[(size_t)d * 1024];
        orow[(size_t)d * 1024] = cv;
        float diff = ze - cv;
        part += diff * diff;
    }
#pragma unroll
    for (int off = 32; off > 0; off >>= 1) part += __shfl_down(part, off);
    if (lane == 0) wsum[w] = part;
    __syncthreads();
    if (tid == 0) {
        float t = (wsum[0] + wsum[1] + wsum[2] + wsum[3]) * (1.25f / 4194304.f);
        atomicAdd(out + 4194304, t);
    }
}

// ================= launcher =================
extern "C" void kernel_launch(void* const* d_in, const int* in_sizes, int n_in,
                              void* d_out, int out_size, void* d_ws, size_t ws_size,
                              hipStream_t stream) {
    const float* z = (const float*)d_in[0];
    const float* cb = (const float*)d_in[1];
    float* out = (float*)d_out;
    char* wsb = (char*)d_ws;

    if (ws_size >= WS_NEED) {
        float* zn = (float*)(wsb + ZN_B);
        float* mrg = (float*)(wsb + MRG_B);
        int* codes = (int*)(wsb + CODES_B);
        unsigned* cnt = (unsigned*)(wsb + CNT_B);
        unsigned* tau_g = (unsigned*)(wsb + TAU_B);
        int* cand = (int*)(wsb + CANDI_B);
        unsigned short* zh = (unsigned short*)(wsb + ZH_B);
        unsigned short* ch = (unsigned short*)(wsb + CH_B);

        hipMemsetAsync(wsb + CNT_B, 0, 131072, stream);      // cnt + tau (key 0 = -inf)
        hipMemsetAsync(out + 4194304, 0, sizeof(float), stream);

        znorm_kernel<<<64, 256, 0, stream>>>(z, zn, mrg);
        split_z_kernel<<<dim3(16, 4, 16), 256, 0, stream>>>(z, zh);
        split_c_kernel<<<2048, 256, 0, stream>>>(cb, ch);
        gemm_screen32<<<256, 512, 0, stream>>>(zh, ch, mrg, tau_g, cnt, cand);
        select_kernel<<<4096, 256, 0, stream>>>(z, cb, zn, cnt, cand, codes, out + 4194305);
        finalize2_kernel<<<256, 256, 0, stream>>>(z, cb, codes, out);
    } else {
        float* zn = (float*)wsb;
        float* mrgdummy = (float*)(wsb + 65536);
        float* pscore = (float*)wsb + PSCORE_OFF + 16384;   // keep clear of zn/mrg
        int* pidx = (int*)((float*)wsb + PIDX_OFF + 16384);
        znorm_kernel<<<64, 256, 0, stream>>>(z, zn, mrgdummy);
        dim3 grid(16384 / NT, KS);
        dist_argmin_kernel<<<grid, 256, 0, stream>>>(z, cb, zn, pscore, pidx);
        hipMemsetAsync(out + 4194304, 0, sizeof(float), stream);
        finalize_kernel<<<16384 / 64, 256, 0, stream>>>(z, cb, pscore, pidx, out);
    }
}

// Round 5
// 628.409 us; speedup vs baseline: 1.4235x; 1.4235x over previous
//
#include <hip/hip_runtime.h>

// VQ codebook: z_e (16,256,32,32) f32, codebook (8192,256) f32.
// out f32: z_q_st[4194304] | loss[1] | codes[16384].
// n = b*1024+hw; z_flat[n][d] = z_e[b*262144 + d*1024 + hw]
// Reference: dist = fl32(zz - 2*dot), dot = sequential f32 FMA chain d=0..255,
// argmin ties -> lowest index (validated bitwise in round 2; the f32 subtract
// zz - 2*dot reproduces the reference's score quantization exactly).
//
// Pipeline: bf16 hh-only MFMA screen (32x32x16, z register-stationary,
// codebook streamed through 64KB LDS) -> per-row fresh threshold via
// atomic-RETURN (L1-safe; round-4's plain-load-of-atomic was the bug) ->
// candidate append -> fused exact-rescore + z_q/loss with LDS-staged z.

#define CAP 64

typedef short bf16x8 __attribute__((ext_vector_type(8)));
typedef float f32x16 __attribute__((ext_vector_type(16)));

__device__ __forceinline__ unsigned short f2bf(float f) {
    unsigned u = __float_as_uint(f);
    return (unsigned short)((u + 0x7fffu + ((u >> 16) & 1u)) >> 16);
}
__device__ __forceinline__ float ulpf(float x) {   // 2^(exp(x)-23), x normal positive
    return __uint_as_float((__float_as_uint(x) & 0x7f800000u) - (23u << 23));
}
// monotone float<->uint key (total order matches float order)
__device__ __forceinline__ unsigned fkey(float f) {
    unsigned u = __float_as_uint(f);
    return (u & 0x80000000u) ? ~u : (u | 0x80000000u);
}
__device__ __forceinline__ float funkey(unsigned k) {
    unsigned u = (k & 0x80000000u) ? (k ^ 0x80000000u) : ~k;
    return __uint_as_float(u);
}

// ---- ws byte layout (big path) ----
#define ZN_B      0u          // f32[16384]
#define MRG_B     65536u      // f32[16384]  (dot-domain margin)
#define CNT_B     131072u     // u32[16384]
#define TAU_B     196608u     // u32[16384]  (fkey of row max dot)
#define CAND_B    262144u     // i32[16384*CAP] = 4 MB
#define ZH_B      4456448u    // bf16[16384][256] = 8 MB
#define CH_B      12845056u   // bf16[8192][256] = 4 MB
#define WS_NEED   17039360u

// ---------------- znorm + margin ----------------
__global__ __launch_bounds__(256)
void znorm_kernel(const float* __restrict__ z, float* __restrict__ zn,
                  float* __restrict__ mrg) {
    int n = blockIdx.x * 256 + threadIdx.x;
    int b = n >> 10, hw = n & 1023;
    const float* zp = z + (size_t)b * 262144 + hw;
    float s = 0.f;
    for (int d = 0; d < 256; ++d) {
        float v = zp[(size_t)d << 10];
        s += v * v;
    }
    zn[n] = s;
    // dot-domain margin: ref tie-cell (ulp(zz) score => ulp/2 dot, x1.5 binade
    // slack) + 2*deterministic bf16-split screen error bound (~5e-5 each)
    mrg[n] = 1.5f * ulpf(s) + 1.5e-4f;
}

// ---------------- prep: z -> bf16 with transpose ----------------
__global__ __launch_bounds__(256)
void split_z_kernel(const float* __restrict__ z, unsigned short* __restrict__ zh) {
    __shared__ float t[64][65];
    const int b = blockIdx.z, hw0 = blockIdx.x * 64, d0 = blockIdx.y * 64;
    const int c = threadIdx.x & 63, rg = threadIdx.x >> 6;
#pragma unroll
    for (int it = 0; it < 16; ++it) {
        int dl = it * 4 + rg;
        t[dl][c] = z[(size_t)b * 262144 + (size_t)(d0 + dl) * 1024 + hw0 + c];
    }
    __syncthreads();
#pragma unroll
    for (int it = 0; it < 16; ++it) {
        int nl = it * 4 + rg;
        zh[(size_t)(b * 1024 + hw0 + nl) * 256 + d0 + c] = f2bf(t[c][nl]);
    }
}

// ---------------- prep: codebook -> bf16 ----------------
__global__ __launch_bounds__(256)
void split_c_kernel(const float* __restrict__ cb, unsigned short* __restrict__ ch) {
    int gid = blockIdx.x * 256 + threadIdx.x;     // float4 index; 524288 total
    float4 v = ((const float4*)cb)[gid];
    ushort4 hv;
    hv.x = f2bf(v.x); hv.y = f2bf(v.y); hv.z = f2bf(v.z); hv.w = f2bf(v.w);
    ((ushort4*)ch)[gid] = hv;
}

// ---------------- screening GEMM (32x32x16, z stationary) ----------------
// 256 blocks x 512 thr (8 waves = 2 rowgroups x 4 code-quarters).
// Block owns 64 z-rows; streams all 8192 codes in 64 tiles of 128.
__global__ __launch_bounds__(512, 2)
void gemm_screen32(const unsigned short* __restrict__ zh,
                   const unsigned short* __restrict__ ch,
                   const float* __restrict__ mrg,
                   unsigned* __restrict__ tau_g, unsigned* __restrict__ cnt,
                   int* __restrict__ cand) {
    __shared__ char buf[65536];   // 128 codes x 512B (xor-granule swizzled)
    const int tid = threadIdx.x;
    const int l = tid & 63;
    const int wv = tid >> 6;
    const int rg = wv >> 2;       // row-group (0..1)
    const int cq = wv & 3;        // code-quarter (0..3)
    const int l5 = l >> 5, l31 = l & 31;
    const int n0 = blockIdx.x * 64;

    // A fragments: 32 z-rows x all 256 d in registers.
    // 32x32x16 A-frag: lane holds A[row=l&31][k = 8*(l>>5) + j]
    bf16x8 a[16];
    {
        const unsigned short* zrow = zh + (size_t)(n0 + rg * 32 + l31) * 256;
#pragma unroll
        for (int k = 0; k < 16; ++k)
            a[k] = *(const bf16x8*)(zrow + k * 16 + l5 * 8);
    }

    // per-register row mapping (C/D: row = (reg&3) + 8*(reg>>2) + 4*l5)
    float best[16], tau[16], mrg_r[16];
#pragma unroll
    for (int r = 0; r < 16; ++r) {
        int n = n0 + rg * 32 + 4 * l5 + (r & 3) + 8 * (r >> 2);
        best[r] = -3.0e38f;
        tau[r] = 3.0e38f;           // no appends until first refresh (t=0)
        mrg_r[r] = mrg[n];
    }

    // staging registers + prologue stage of tile 0
    uint4 st[8];
#pragma unroll
    for (int j = 0; j < 8; ++j) {
        int c = j * 16 + (tid >> 5);
        int slog = (tid & 31) ^ (c & 31);
        st[j] = *(const uint4*)(ch + (size_t)c * 256 + slog * 8);
    }
#pragma unroll
    for (int j = 0; j < 8; ++j)
        *(uint4*)(buf + j * 8192 + tid * 16) = st[j];
    __syncthreads();

    for (int t = 0; t < 64; ++t) {
        // issue next tile's loads early (hide under MFMA)
        if (t < 63) {
            const int code0 = (t + 1) * 128;
#pragma unroll
            for (int j = 0; j < 8; ++j) {
                int c = j * 16 + (tid >> 5);
                int slog = (tid & 31) ^ (c & 31);
                st[j] = *(const uint4*)(ch + (size_t)(code0 + c) * 256 + slog * 8);
            }
        }
        // compute: 16 d-chunks, 2 independent MFMA chains
        f32x16 accA, accB;
#pragma unroll
        for (int r = 0; r < 16; ++r) { accA[r] = 0.f; accB[r] = 0.f; }
        const int cbyte = (cq * 32 + l31) * 512;
#pragma unroll
        for (int k = 0; k < 16; k += 2) {
            bf16x8 b0 = *(const bf16x8*)(buf + cbyte + (((2 * k + l5) ^ l31) << 4));
            bf16x8 b1 = *(const bf16x8*)(buf + cbyte + (((2 * (k + 1) + l5) ^ l31) << 4));
            accA = __builtin_amdgcn_mfma_f32_32x32x16_bf16(a[k], b0, accA, 0, 0, 0);
            accB = __builtin_amdgcn_mfma_f32_32x32x16_bf16(a[k + 1], b1, accB, 0, 0, 0);
        }
        float s[16];
#pragma unroll
        for (int r = 0; r < 16; ++r) {
            s[r] = accA[r] + accB[r];
            best[r] = fmaxf(best[r], s[r]);
        }
        // refresh tau every 4 tiles via atomic RETURN VALUE (L1-safe fresh read)
        if ((t == 0) || ((t & 3) == 3)) {
#pragma unroll
            for (int r = 0; r < 16; ++r) {
                float m = best[r];
#pragma unroll
                for (int msk = 1; msk <= 16; msk <<= 1)
                    m = fmaxf(m, __shfl_xor(m, msk));
                float fresh = 0.f;
                if (l31 == 0) {
                    int n = n0 + rg * 32 + 4 * l5 + (r & 3) + 8 * (r >> 2);
                    unsigned old = atomicMax(&tau_g[n], fkey(m));
                    fresh = (old == 0u) ? m : fmaxf(funkey(old), m);
                }
                fresh = __shfl(fresh, l & 32);
                tau[r] = fresh - mrg_r[r];
            }
        }
        // candidate appends (rare; tau is a valid lower-bound threshold)
        {
            const int code = t * 128 + cq * 32 + l31;
#pragma unroll
            for (int r = 0; r < 16; ++r) {
                if (s[r] >= tau[r]) {
                    int n = n0 + rg * 32 + 4 * l5 + (r & 3) + 8 * (r >> 2);
                    unsigned slot = atomicAdd(&cnt[n], 1u);
                    if (slot < CAP) cand[n * CAP + slot] = code;
                }
            }
        }
        __syncthreads();   // buf reads done
        if (t < 63) {
#pragma unroll
            for (int j = 0; j < 8; ++j)
                *(uint4*)(buf + j * 8192 + tid * 16) = st[j];
        }
        __syncthreads();   // next tile staged
    }
}

// ---------------- fused exact rescore + z_q gather + loss ----------------
// 256 blocks x 256 thr; block owns 64 rows (same b, consecutive hw -> all
// global z accesses coalesced). z rows staged once in LDS.
__global__ __launch_bounds__(256)
void select_finalize(const float* __restrict__ z, const float* __restrict__ cb,
                     const float* __restrict__ zn, const unsigned* __restrict__ cnt,
                     const int* __restrict__ cand,
                     float* __restrict__ out) {
    __shared__ float zs[64][257];
    __shared__ int codes_s[64];
    __shared__ float wsum[4];
    const int tid = threadIdx.x;
    const int nbase = blockIdx.x * 64;
    const int b = nbase >> 10, hw0 = nbase & 1023;
    const int lane = tid & 63;
    const int w = tid >> 6;

    // stage 64 rows x 256 d, coalesced (lanes = consecutive hw)
#pragma unroll 8
    for (int it = 0; it < 64; ++it) {
        int d = it * 4 + w;
        zs[lane][d] = z[(size_t)b * 262144 + (size_t)d * 1024 + hw0 + lane];
    }
    __syncthreads();

    // rescore: wave w handles rows w*16 .. w*16+15
#pragma unroll 1
    for (int rr = 0; rr < 16; ++rr) {
        const int ridx = w * 16 + rr;
        const int n = nbase + ridx;
        const unsigned c = cnt[n];
        const float zz = zn[n];
        float bs; int bi;
        if (c > 0 && c <= CAP) {
            float ss = 3.0e38f; int myk = 0x7fffffff;
            if (lane < (int)c) {
                myk = cand[n * CAP + lane];
                const float* cr = cb + (size_t)myk * 256;
                float dot = 0.f;
#pragma unroll 8
                for (int d4 = 0; d4 < 64; ++d4) {   // exact sequential chain
                    float4 cv = ((const float4*)cr)[d4];
                    dot = fmaf(zs[ridx][d4 * 4 + 0], cv.x, dot);
                    dot = fmaf(zs[ridx][d4 * 4 + 1], cv.y, dot);
                    dot = fmaf(zs[ridx][d4 * 4 + 2], cv.z, dot);
                    dot = fmaf(zs[ridx][d4 * 4 + 3], cv.w, dot);
                }
                ss = zz - 2.0f * dot;   // reproduces reference score rounding
            }
            bs = ss; bi = myk;
        } else {
            // overflow/empty fallback: exact full scan (expected never)
            bs = 3.0e38f; bi = 0x7fffffff;
            for (int base = 0; base < 8192; base += 64) {
                const float* cr = cb + (size_t)(base + lane) * 256;
                float dot = 0.f;
#pragma unroll 8
                for (int d4 = 0; d4 < 64; ++d4) {
                    float4 cv = ((const float4*)cr)[d4];
                    dot = fmaf(zs[ridx][d4 * 4 + 0], cv.x, dot);
                    dot = fmaf(zs[ridx][d4 * 4 + 1], cv.y, dot);
                    dot = fmaf(zs[ridx][d4 * 4 + 2], cv.z, dot);
                    dot = fmaf(zs[ridx][d4 * 4 + 3], cv.w, dot);
                }
                float sc = zz - 2.0f * dot;
                int k = base + lane;
                if (sc < bs || (sc == bs && k < bi)) { bs = sc; bi = k; }
            }
        }
#pragma unroll
        for (int m = 1; m <= 32; m <<= 1) {
            float ps = __shfl_xor(bs, m);
            int pi = __shfl_xor(bi, m);
            if (ps < bs || (ps == bs && pi < bi)) { bs = ps; bi = pi; }
        }
        if (lane == 0) { codes_s[ridx] = bi; out[4194305 + n] = (float)bi; }
    }
    __syncthreads();

    // z_q gather + loss; lane = row, wave = d-quadrant
    const int code = codes_s[lane];
    const float* crow = cb + (size_t)code * 256;
    float part = 0.f;
#pragma unroll 8
    for (int j = 0; j < 64; ++j) {
        int d = w * 64 + j;
        float cv = crow[d];
        float ze = zs[lane][d];
        out[(size_t)b * 262144 + (size_t)d * 1024 + hw0 + lane] = cv;
        float diff = ze - cv;
        part += diff * diff;
    }
#pragma unroll
    for (int off = 32; off > 0; off >>= 1) part += __shfl_down(part, off);
    if (lane == 0) wsum[w] = part;
    __syncthreads();
    if (tid == 0) {
        float t = (wsum[0] + wsum[1] + wsum[2] + wsum[3]) * (1.25f / 4194304.f);
        atomicAdd(out + 4194304, t);
    }
}

// ================= fallback path (round-2 kernels, ws-small case) =================
#define NT 128
#define KT 128
#define DC 64
#define KS 4
#define KRANGE (8192 / KS)
#define PSCORE_OFF 32768
#define PIDX_OFF (32768 + KS * 16384)

__global__ __launch_bounds__(256, 2)
void dist_argmin_kernel(const float* __restrict__ z, const float* __restrict__ cb,
                        const float* __restrict__ zn,
                        float* __restrict__ pscore, int* __restrict__ pidx) {
    __shared__ float zs[DC][NT];
    __shared__ float cs[DC][KT];
    const int tid = threadIdx.x;
    const int tn = tid & 15;
    const int tk = tid >> 4;
    const int n0 = blockIdx.x * NT;
    const int b = n0 >> 10;
    const int hw0 = n0 & 1023;
    const float* zb = z + (size_t)b * 262144 + hw0;
    const int k0base = blockIdx.y * KRANGE;
    float zzr[8];
#pragma unroll
    for (int i = 0; i < 8; ++i) {
        int row = (i < 4) ? (tn * 4 + i) : (64 + tn * 4 + (i - 4));
        zzr[i] = zn[n0 + row];
    }
    float best[8]; int bidx[8];
#pragma unroll
    for (int i = 0; i < 8; ++i) { best[i] = 3.0e38f; bidx[i] = 0; }
    for (int kt = 0; kt < KRANGE / KT; ++kt) {
        const int k0 = k0base + kt * KT;
        float acc[8][8];
#pragma unroll
        for (int i = 0; i < 8; ++i)
#pragma unroll
            for (int j = 0; j < 8; ++j) acc[i][j] = 0.f;
        for (int dc = 0; dc < 256; dc += DC) {
            __syncthreads();
#pragma unroll
            for (int it = 0; it < 8; ++it) {
                int idx = it * 256 + tid;
                int d = idx >> 5, nv = idx & 31;
                float4 v = *(const float4*)(zb + (size_t)(dc + d) * 1024 + nv * 4);
                *(float4*)&zs[d][nv * 4] = v;
            }
#pragma unroll
            for (int it = 0; it < 8; ++it) {
                int idx = it * 256 + tid;
                int k = idx >> 4, dv = idx & 15;
                float4 v = *(const float4*)(cb + (size_t)(k0 + k) * 256 + dc + dv * 4);
                int colv = k ^ ((dv & 7) << 2);
                cs[dv * 4 + 0][colv] = v.x;
                cs[dv * 4 + 1][colv] = v.y;
                cs[dv * 4 + 2][colv] = v.z;
                cs[dv * 4 + 3][colv] = v.w;
            }
            __syncthreads();
#pragma unroll 2
            for (int d = 0; d < DC; ++d) {
                int swz = ((d >> 2) & 7) << 2;
                float4 a0 = *(const float4*)&zs[d][tn * 4];
                float4 a1 = *(const float4*)&zs[d][64 + tn * 4];
                float4 b0 = *(const float4*)&cs[d][(tk * 4) ^ swz];
                float4 b1 = *(const float4*)&cs[d][(64 + tk * 4) ^ swz];
                float av[8] = {a0.x, a0.y, a0.z, a0.w, a1.x, a1.y, a1.z, a1.w};
                float bv[8] = {b0.x, b0.y, b0.z, b0.w, b1.x, b1.y, b1.z, b1.w};
#pragma unroll
                for (int i = 0; i < 8; ++i)
#pragma unroll
                    for (int j = 0; j < 8; ++j)
                        acc[i][j] = fmaf(av[i], bv[j], acc[i][j]);
            }
        }
#pragma unroll
        for (int j = 0; j < 8; ++j) {
            int kloc = (j < 4) ? (tk * 4 + j) : (64 + tk * 4 + (j - 4));
            int kk = k0 + kloc;
#pragma unroll
            for (int i = 0; i < 8; ++i) {
                float s = zzr[i] - 2.0f * acc[i][j];
                if (s < best[i]) { best[i] = s; bidx[i] = kk; }
            }
        }
    }
    __syncthreads();
    float* sredf = &zs[0][0];
    int* sredi = (int*)&cs[0][0];
#pragma unroll
    for (int i = 0; i < 8; ++i) {
        int row = (i < 4) ? (tn * 4 + i) : (64 + tn * 4 + (i - 4));
        sredf[row * 16 + tk] = best[i];
        sredi[row * 16 + tk] = bidx[i];
    }
    __syncthreads();
    if (tid < NT) {
        float bs = sredf[tid * 16];
        int bi = sredi[tid * 16];
#pragma unroll
        for (int t = 1; t < 16; ++t) {
            float s = sredf[tid * 16 + t];
            int ix = sredi[tid * 16 + t];
            if (s < bs || (s == bs && ix < bi)) { bs = s; bi = ix; }
        }
        pscore[blockIdx.y * 16384 + n0 + tid] = bs;
        pidx[blockIdx.y * 16384 + n0 + tid] = bi;
    }
}

__global__ __launch_bounds__(256)
void finalize_kernel(const float* __restrict__ z, const float* __restrict__ cb,
                     const float* __restrict__ pscore, const int* __restrict__ pidx,
                     float* __restrict__ out) {
    __shared__ int codes_s[64];
    __shared__ float wsum[4];
    const int nbase = blockIdx.x * 64;
    const int tid = threadIdx.x;
    if (tid < 64) {
        int n = nbase + tid;
        float bs = pscore[n];
        int bi = pidx[n];
#pragma unroll
        for (int p = 1; p < KS; ++p) {
            float s = pscore[p * 16384 + n];
            int ix = pidx[p * 16384 + n];
            if (s < bs || (s == bs && ix < bi)) { bs = s; bi = ix; }
        }
        codes_s[tid] = bi;
        out[4194305 + n] = (float)bi;
    }
    __syncthreads();
    const int lane = tid & 63;
    const int w = tid >> 6;
    const int n = nbase + lane;
    const int b = n >> 10, hw = n & 1023;
    const int code = codes_s[lane];
    const float* crow = cb + (size_t)code * 256;
    const float* zrow = z + (size_t)b * 262144 + hw;
    float* orow = out + (size_t)b * 262144 + hw;
    float part = 0.f;
    for (int j = 0; j < 64; ++j) {
        int d = w * 64 + j;
        float cv = crow[d];
        float ze = zrow[(size_t)d * 1024];
        orow[(size_t)d * 1024] = cv;
        float diff = ze - cv;
        part += diff * diff;
    }
#pragma unroll
    for (int off = 32; off > 0; off >>= 1) part += __shfl_down(part, off);
    if (lane == 0) wsum[w] = part;
    __syncthreads();
    if (tid == 0) {
        float t = (wsum[0] + wsum[1] + wsum[2] + wsum[3]) * (1.25f / 4194304.f);
        atomicAdd(out + 4194304, t);
    }
}

// ================= launcher =================
extern "C" void kernel_launch(void* const* d_in, const int* in_sizes, int n_in,
                              void* d_out, int out_size, void* d_ws, size_t ws_size,
                              hipStream_t stream) {
    const float* z = (const float*)d_in[0];
    const float* cb = (const float*)d_in[1];
    float* out = (float*)d_out;
    char* wsb = (char*)d_ws;

    if (ws_size >= WS_NEED) {
        float* zn = (float*)(wsb + ZN_B);
        float* mrg = (float*)(wsb + MRG_B);
        unsigned* cnt = (unsigned*)(wsb + CNT_B);
        unsigned* tau_g = (unsigned*)(wsb + TAU_B);
        int* cand = (int*)(wsb + CAND_B);
        unsigned short* zh = (unsigned short*)(wsb + ZH_B);
        unsigned short* ch = (unsigned short*)(wsb + CH_B);

        hipMemsetAsync(wsb + CNT_B, 0, 131072, stream);   // cnt + tau (key 0)
        hipMemsetAsync(out + 4194304, 0, sizeof(float), stream);

        znorm_kernel<<<64, 256, 0, stream>>>(z, zn, mrg);
        split_z_kernel<<<dim3(16, 4, 16), 256, 0, stream>>>(z, zh);
        split_c_kernel<<<2048, 256, 0, stream>>>(cb, ch);
        gemm_screen32<<<256, 512, 0, stream>>>(zh, ch, mrg, tau_g, cnt, cand);
        select_finalize<<<256, 256, 0, stream>>>(z, cb, zn, cnt, cand, out);
    } else {
        float* zn = (float*)wsb;
        float* mrgdummy = (float*)(wsb + 65536);
        float* pscore = (float*)wsb + PSCORE_OFF;
        int* pidx = (int*)((float*)wsb + PIDX_OFF);
        znorm_kernel<<<64, 256, 0, stream>>>(z, zn, mrgdummy);
        dim3 grid(16384 / NT, KS);
        dist_argmin_kernel<<<grid, 256, 0, stream>>>(z, cb, zn, pscore, pidx);
        hipMemsetAsync(out + 4194304, 0, sizeof(float), stream);
        finalize_kernel<<<16384 / 64, 256, 0, stream>>>(z, cb, pscore, pidx, out);
    }
}

// Round 6
// 417.468 us; speedup vs baseline: 2.1428x; 1.5053x over previous
//
#include <hip/hip_runtime.h>

// VQ codebook: z_e (16,256,32,32) f32, codebook (8192,256) f32.
// out f32: z_q_st[4194304] | loss[1] | codes[16384].
// n = b*1024+hw; z_flat[n][d] = z_e[b*262144 + d*1024 + hw]
// Reference: dist = fl32(zz - 2*dot), dot = sequential f32 FMA chain d=0..255,
// argmin ties -> lowest index (validated bitwise in round 2).
//
// Pipeline: bf16 hh-only MFMA screen (32x32x16, z register-stationary,
// codebook double-buffered through 128KB LDS via global_load_lds with
// source-side XOR granule swizzle) -> fresh per-row threshold via atomic
// RETURN value -> candidate append -> fused exact rescore + z_q/loss.
// Round-6 fix: r5 spilled ~90 VGPRs/thread (WRITE_SIZE 571MB of scratch);
// staging regs removed via global_load_lds, 1 block/CU -> no spill.

#define CAP 64

typedef short bf16x8 __attribute__((ext_vector_type(8)));
typedef float f32x16 __attribute__((ext_vector_type(16)));

__device__ __forceinline__ unsigned short f2bf(float f) {
    unsigned u = __float_as_uint(f);
    return (unsigned short)((u + 0x7fffu + ((u >> 16) & 1u)) >> 16);
}
__device__ __forceinline__ float ulpf(float x) {   // 2^(exp(x)-23), x normal positive
    return __uint_as_float((__float_as_uint(x) & 0x7f800000u) - (23u << 23));
}
// monotone float<->uint key (total order matches float order)
__device__ __forceinline__ unsigned fkey(float f) {
    unsigned u = __float_as_uint(f);
    return (u & 0x80000000u) ? ~u : (u | 0x80000000u);
}
__device__ __forceinline__ float funkey(unsigned k) {
    unsigned u = (k & 0x80000000u) ? (k ^ 0x80000000u) : ~k;
    return __uint_as_float(u);
}
__device__ __forceinline__ void gload_lds16(const void* g, void* l) {
    __builtin_amdgcn_global_load_lds(
        (const __attribute__((address_space(1))) void*)g,
        (__attribute__((address_space(3))) void*)l, 16, 0, 0);
}

// ---- ws byte layout (big path) ----
#define ZN_B      0u          // f32[16384]
#define MRG_B     65536u      // f32[16384]  (dot-domain margin)
#define CNT_B     131072u     // u32[16384]
#define TAU_B     196608u     // u32[16384]  (fkey of row max dot)
#define CAND_B    262144u     // i32[16384*CAP] = 4 MB
#define ZH_B      4456448u    // bf16[16384][256] = 8 MB
#define CH_B      12845056u   // bf16[8192][256] = 4 MB
#define WS_NEED   17039360u

// ---------------- znorm + margin ----------------
__global__ __launch_bounds__(256)
void znorm_kernel(const float* __restrict__ z, float* __restrict__ zn,
                  float* __restrict__ mrg) {
    int n = blockIdx.x * 256 + threadIdx.x;
    int b = n >> 10, hw = n & 1023;
    const float* zp = z + (size_t)b * 262144 + hw;
    float s = 0.f;
    for (int d = 0; d < 256; ++d) {
        float v = zp[(size_t)d << 10];
        s += v * v;
    }
    zn[n] = s;
    // dot-domain margin: ref tie-cell + 2*deterministic bf16 screen error bound
    mrg[n] = 1.5f * ulpf(s) + 1.5e-4f;
}

// ---------------- prep: z -> bf16 with transpose ----------------
__global__ __launch_bounds__(256)
void split_z_kernel(const float* __restrict__ z, unsigned short* __restrict__ zh) {
    __shared__ float t[64][65];
    const int b = blockIdx.z, hw0 = blockIdx.x * 64, d0 = blockIdx.y * 64;
    const int c = threadIdx.x & 63, rg = threadIdx.x >> 6;
#pragma unroll
    for (int it = 0; it < 16; ++it) {
        int dl = it * 4 + rg;
        t[dl][c] = z[(size_t)b * 262144 + (size_t)(d0 + dl) * 1024 + hw0 + c];
    }
    __syncthreads();
#pragma unroll
    for (int it = 0; it < 16; ++it) {
        int nl = it * 4 + rg;
        zh[(size_t)(b * 1024 + hw0 + nl) * 256 + d0 + c] = f2bf(t[c][nl]);
    }
}

// ---------------- prep: codebook -> bf16 ----------------
__global__ __launch_bounds__(256)
void split_c_kernel(const float* __restrict__ cb, unsigned short* __restrict__ ch) {
    int gid = blockIdx.x * 256 + threadIdx.x;     // float4 index; 524288 total
    float4 v = ((const float4*)cb)[gid];
    ushort4 hv;
    hv.x = f2bf(v.x); hv.y = f2bf(v.y); hv.z = f2bf(v.z); hv.w = f2bf(v.w);
    ((ushort4*)ch)[gid] = hv;
}

// ---------------- screening GEMM (32x32x16, z stationary) ----------------
// 256 blocks x 512 thr (8 waves = 2 rowgroups x 4 code-quarters).
// Block owns 64 z-rows; streams all 8192 codes in 64 tiles of 128 codes,
// double-buffered 2x64KB LDS, staged by global_load_lds (no staging VGPRs).
__global__ __launch_bounds__(512, 2)
void gemm_screen32(const unsigned short* __restrict__ zh,
                   const unsigned short* __restrict__ ch,
                   const float* __restrict__ mrg,
                   unsigned* __restrict__ tau_g, unsigned* __restrict__ cnt,
                   int* __restrict__ cand) {
    __shared__ char smem[131072];   // 2 x (128 codes x 512B), granule-swizzled
    const int tid = threadIdx.x;
    const int l = tid & 63;
    const int wv = tid >> 6;
    const int rg = wv >> 2;       // row-group (0..1)
    const int cq = wv & 3;        // code-quarter (0..3)
    const int l5 = l >> 5, l31 = l & 31;
    const int n0 = blockIdx.x * 64;

    // A fragments: 32 z-rows x all 256 d in registers.
    // 32x32x16 A-frag: lane holds A[row=l&31][k = 8*(l>>5) + j]  (HW-verified r5)
    bf16x8 a[16];
    {
        const unsigned short* zrow = zh + (size_t)(n0 + rg * 32 + l31) * 256;
#pragma unroll
        for (int k = 0; k < 16; ++k)
            a[k] = *(const bf16x8*)(zrow + k * 16 + l5 * 8);
    }

    // per-lane staging source offsets (shorts), lane-constant across tiles.
    // wave wv stages local codes wv*16+j*2+(l>>5); LDS dest is linear
    // (base+lane*16), so the XOR granule swizzle is applied to the SOURCE:
    // phys granule p=l31 holds global granule p^(cl&31).
    int soff[8];
#pragma unroll
    for (int j = 0; j < 8; ++j) {
        int cl = wv * 16 + j * 2 + l5;
        soff[j] = cl * 256 + ((l31 ^ (cl & 31)) * 8);
    }

    // C/D mapping: row = rg*32 + 4*l5 + (r&3) + 8*(r>>2), col = l31 (HW-verified)
    float best[16], tau[16], mrg_r[16];
#pragma unroll
    for (int r = 0; r < 16; ++r) {
        int n = n0 + rg * 32 + 4 * l5 + (r & 3) + 8 * (r >> 2);
        best[r] = -3.0e38f;
        tau[r] = 3.0e38f;           // no appends until first refresh (t=0)
        mrg_r[r] = mrg[n];
    }

    // prologue: stage tile 0 into buffer 0
#pragma unroll
    for (int j = 0; j < 8; ++j)
        gload_lds16(ch + soff[j], smem + wv * 8192 + j * 1024);

    for (int t = 0; t < 64; ++t) {
        // drains tile t's loads (in flight during previous tile's compute)
        // and guarantees all waves finished reading buf[(t+1)&1] last iter.
        __syncthreads();
        const char* cur = smem + (t & 1) * 65536;
        if (t < 63) {   // issue next tile's loads; they land during compute
            const unsigned short* src = ch + (size_t)(t + 1) * 32768;
            char* nxt = smem + ((t + 1) & 1) * 65536 + wv * 8192;
#pragma unroll
            for (int j = 0; j < 8; ++j)
                gload_lds16(src + soff[j], nxt + j * 1024);
        }
        // compute: 16 chained MFMAs (full-rate accumulator chaining)
        f32x16 acc;
#pragma unroll
        for (int r = 0; r < 16; ++r) acc[r] = 0.f;
        const int lrbase = (cq * 32 + l31) * 512;
#pragma unroll
        for (int k = 0; k < 16; ++k) {
            bf16x8 b = *(const bf16x8*)(cur + lrbase + (((2 * k + l5) ^ l31) << 4));
            acc = __builtin_amdgcn_mfma_f32_32x32x16_bf16(a[k], b, acc, 0, 0, 0);
        }
#pragma unroll
        for (int r = 0; r < 16; ++r) best[r] = fmaxf(best[r], acc[r]);
        // refresh tau every 4 tiles via atomic RETURN VALUE (L1-safe fresh read)
        if ((t == 0) || ((t & 3) == 3)) {
#pragma unroll
            for (int r = 0; r < 16; ++r) {
                float m = best[r];
#pragma unroll
                for (int msk = 1; msk <= 16; msk <<= 1)
                    m = fmaxf(m, __shfl_xor(m, msk));
                float fresh = 0.f;
                if (l31 == 0) {
                    int n = n0 + rg * 32 + 4 * l5 + (r & 3) + 8 * (r >> 2);
                    unsigned old = atomicMax(&tau_g[n], fkey(m));
                    fresh = (old == 0u) ? m : fmaxf(funkey(old), m);
                }
                fresh = __shfl(fresh, l & 32);
                tau[r] = fresh - mrg_r[r];
            }
        }
        // candidate appends (rare; tau is a stale-low-safe threshold)
        {
            const int code = t * 128 + cq * 32 + l31;
#pragma unroll
            for (int r = 0; r < 16; ++r) {
                if (acc[r] >= tau[r]) {
                    int n = n0 + rg * 32 + 4 * l5 + (r & 3) + 8 * (r >> 2);
                    unsigned slot = atomicAdd(&cnt[n], 1u);
                    if (slot < CAP) cand[n * CAP + slot] = code;
                }
            }
        }
    }
}

// ---------------- fused exact rescore + z_q gather + loss ----------------
__global__ __launch_bounds__(256)
void select_finalize(const float* __restrict__ z, const float* __restrict__ cb,
                     const float* __restrict__ zn, const unsigned* __restrict__ cnt,
                     const int* __restrict__ cand,
                     float* __restrict__ out) {
    __shared__ float zs[64][257];
    __shared__ int codes_s[64];
    __shared__ float wsum[4];
    const int tid = threadIdx.x;
    const int nbase = blockIdx.x * 64;
    const int b = nbase >> 10, hw0 = nbase & 1023;
    const int lane = tid & 63;
    const int w = tid >> 6;

    // stage 64 rows x 256 d, coalesced (lanes = consecutive hw)
#pragma unroll 8
    for (int it = 0; it < 64; ++it) {
        int d = it * 4 + w;
        zs[lane][d] = z[(size_t)b * 262144 + (size_t)d * 1024 + hw0 + lane];
    }
    __syncthreads();

    // rescore: wave w handles rows w*16 .. w*16+15
#pragma unroll 1
    for (int rr = 0; rr < 16; ++rr) {
        const int ridx = w * 16 + rr;
        const int n = nbase + ridx;
        const unsigned c = cnt[n];
        const float zz = zn[n];
        float bs; int bi;
        if (c > 0 && c <= CAP) {
            float ss = 3.0e38f; int myk = 0x7fffffff;
            if (lane < (int)c) {
                myk = cand[n * CAP + lane];
                const float* cr = cb + (size_t)myk * 256;
                float dot = 0.f;
#pragma unroll 8
                for (int d4 = 0; d4 < 64; ++d4) {   // exact sequential chain
                    float4 cv = ((const float4*)cr)[d4];
                    dot = fmaf(zs[ridx][d4 * 4 + 0], cv.x, dot);
                    dot = fmaf(zs[ridx][d4 * 4 + 1], cv.y, dot);
                    dot = fmaf(zs[ridx][d4 * 4 + 2], cv.z, dot);
                    dot = fmaf(zs[ridx][d4 * 4 + 3], cv.w, dot);
                }
                ss = zz - 2.0f * dot;   // reproduces reference score rounding
            }
            bs = ss; bi = myk;
        } else {
            // overflow/empty fallback: exact full scan (expected never)
            bs = 3.0e38f; bi = 0x7fffffff;
            for (int base = 0; base < 8192; base += 64) {
                const float* cr = cb + (size_t)(base + lane) * 256;
                float dot = 0.f;
#pragma unroll 8
                for (int d4 = 0; d4 < 64; ++d4) {
                    float4 cv = ((const float4*)cr)[d4];
                    dot = fmaf(zs[ridx][d4 * 4 + 0], cv.x, dot);
                    dot = fmaf(zs[ridx][d4 * 4 + 1], cv.y, dot);
                    dot = fmaf(zs[ridx][d4 * 4 + 2], cv.z, dot);
                    dot = fmaf(zs[ridx][d4 * 4 + 3], cv.w, dot);
                }
                float sc = zz - 2.0f * dot;
                int k = base + lane;
                if (sc < bs || (sc == bs && k < bi)) { bs = sc; bi = k; }
            }
        }
#pragma unroll
        for (int m = 1; m <= 32; m <<= 1) {
            float ps = __shfl_xor(bs, m);
            int pi = __shfl_xor(bi, m);
            if (ps < bs || (ps == bs && pi < bi)) { bs = ps; bi = pi; }
        }
        if (lane == 0) { codes_s[ridx] = bi; out[4194305 + n] = (float)bi; }
    }
    __syncthreads();

    // z_q gather + loss; lane = row, wave = d-quadrant
    const int code = codes_s[lane];
    const float* crow = cb + (size_t)code * 256;
    float part = 0.f;
#pragma unroll 8
    for (int j = 0; j < 64; ++j) {
        int d = w * 64 + j;
        float cv = crow[d];
        float ze = zs[lane][d];
        out[(size_t)b * 262144 + (size_t)d * 1024 + hw0 + lane] = cv;
        float diff = ze - cv;
        part += diff * diff;
    }
#pragma unroll
    for (int off = 32; off > 0; off >>= 1) part += __shfl_down(part, off);
    if (lane == 0) wsum[w] = part;
    __syncthreads();
    if (tid == 0) {
        float t = (wsum[0] + wsum[1] + wsum[2] + wsum[3]) * (1.25f / 4194304.f);
        atomicAdd(out + 4194304, t);
    }
}

// ================= fallback path (round-2 kernels, ws-small case) =================
#define NT 128
#define KT 128
#define DC 64
#define KS 4
#define KRANGE (8192 / KS)
#define PSCORE_OFF 32768
#define PIDX_OFF (32768 + KS * 16384)

__global__ __launch_bounds__(256, 2)
void dist_argmin_kernel(const float* __restrict__ z, const float* __restrict__ cb,
                        const float* __restrict__ zn,
                        float* __restrict__ pscore, int* __restrict__ pidx) {
    __shared__ float zs[DC][NT];
    __shared__ float cs[DC][KT];
    const int tid = threadIdx.x;
    const int tn = tid & 15;
    const int tk = tid >> 4;
    const int n0 = blockIdx.x * NT;
    const int b = n0 >> 10;
    const int hw0 = n0 & 1023;
    const float* zb = z + (size_t)b * 262144 + hw0;
    const int k0base = blockIdx.y * KRANGE;
    float zzr[8];
#pragma unroll
    for (int i = 0; i < 8; ++i) {
        int row = (i < 4) ? (tn * 4 + i) : (64 + tn * 4 + (i - 4));
        zzr[i] = zn[n0 + row];
    }
    float best[8]; int bidx[8];
#pragma unroll
    for (int i = 0; i < 8; ++i) { best[i] = 3.0e38f; bidx[i] = 0; }
    for (int kt = 0; kt < KRANGE / KT; ++kt) {
        const int k0 = k0base + kt * KT;
        float acc[8][8];
#pragma unroll
        for (int i = 0; i < 8; ++i)
#pragma unroll
            for (int j = 0; j < 8; ++j) acc[i][j] = 0.f;
        for (int dc = 0; dc < 256; dc += DC) {
            __syncthreads();
#pragma unroll
            for (int it = 0; it < 8; ++it) {
                int idx = it * 256 + tid;
                int d = idx >> 5, nv = idx & 31;
                float4 v = *(const float4*)(zb + (size_t)(dc + d) * 1024 + nv * 4);
                *(float4*)&zs[d][nv * 4] = v;
            }
#pragma unroll
            for (int it = 0; it < 8; ++it) {
                int idx = it * 256 + tid;
                int k = idx >> 4, dv = idx & 15;
                float4 v = *(const float4*)(cb + (size_t)(k0 + k) * 256 + dc + dv * 4);
                int colv = k ^ ((dv & 7) << 2);
                cs[dv * 4 + 0][colv] = v.x;
                cs[dv * 4 + 1][colv] = v.y;
                cs[dv * 4 + 2][colv] = v.z;
                cs[dv * 4 + 3][colv] = v.w;
            }
            __syncthreads();
#pragma unroll 2
            for (int d = 0; d < DC; ++d) {
                int swz = ((d >> 2) & 7) << 2;
                float4 a0 = *(const float4*)&zs[d][tn * 4];
                float4 a1 = *(const float4*)&zs[d][64 + tn * 4];
                float4 b0 = *(const float4*)&cs[d][(tk * 4) ^ swz];
                float4 b1 = *(const float4*)&cs[d][(64 + tk * 4) ^ swz];
                float av[8] = {a0.x, a0.y, a0.z, a0.w, a1.x, a1.y, a1.z, a1.w};
                float bv[8] = {b0.x, b0.y, b0.z, b0.w, b1.x, b1.y, b1.z, b1.w};
#pragma unroll
                for (int i = 0; i < 8; ++i)
#pragma unroll
                    for (int j = 0; j < 8; ++j)
                        acc[i][j] = fmaf(av[i], bv[j], acc[i][j]);
            }
        }
#pragma unroll
        for (int j = 0; j < 8; ++j) {
            int kloc = (j < 4) ? (tk * 4 + j) : (64 + tk * 4 + (j - 4));
            int kk = k0 + kloc;
#pragma unroll
            for (int i = 0; i < 8; ++i) {
                float s = zzr[i] - 2.0f * acc[i][j];
                if (s < best[i]) { best[i] = s; bidx[i] = kk; }
            }
        }
    }
    __syncthreads();
    float* sredf = &zs[0][0];
    int* sredi = (int*)&cs[0][0];
#pragma unroll
    for (int i = 0; i < 8; ++i) {
        int row = (i < 4) ? (tn * 4 + i) : (64 + tn * 4 + (i - 4));
        sredf[row * 16 + tk] = best[i];
        sredi[row * 16 + tk] = bidx[i];
    }
    __syncthreads();
    if (tid < NT) {
        float bs = sredf[tid * 16];
        int bi = sredi[tid * 16];
#pragma unroll
        for (int t = 1; t < 16; ++t) {
            float s = sredf[tid * 16 + t];
            int ix = sredi[tid * 16 + t];
            if (s < bs || (s == bs && ix < bi)) { bs = s; bi = ix; }
        }
        pscore[blockIdx.y * 16384 + n0 + tid] = bs;
        pidx[blockIdx.y * 16384 + n0 + tid] = bi;
    }
}

__global__ __launch_bounds__(256)
void finalize_kernel(const float* __restrict__ z, const float* __restrict__ cb,
                     const float* __restrict__ pscore, const int* __restrict__ pidx,
                     float* __restrict__ out) {
    __shared__ int codes_s[64];
    __shared__ float wsum[4];
    const int nbase = blockIdx.x * 64;
    const int tid = threadIdx.x;
    if (tid < 64) {
        int n = nbase + tid;
        float bs = pscore[n];
        int bi = pidx[n];
#pragma unroll
        for (int p = 1; p < KS; ++p) {
            float s = pscore[p * 16384 + n];
            int ix = pidx[p * 16384 + n];
            if (s < bs || (s == bs && ix < bi)) { bs = s; bi = ix; }
        }
        codes_s[tid] = bi;
        out[4194305 + n] = (float)bi;
    }
    __syncthreads();
    const int lane = tid & 63;
    const int w = tid >> 6;
    const int n = nbase + lane;
    const int b = n >> 10, hw = n & 1023;
    const int code = codes_s[lane];
    const float* crow = cb + (size_t)code * 256;
    const float* zrow = z + (size_t)b * 262144 + hw;
    float* orow = out + (size_t)b * 262144 + hw;
    float part = 0.f;
    for (int j = 0; j < 64; ++j) {
        int d = w * 64 + j;
        float cv = crow[d];
        float ze = zrow[(size_t)d * 1024];
        orow[(size_t)d * 1024] = cv;
        float diff = ze - cv;
        part += diff * diff;
    }
#pragma unroll
    for (int off = 32; off > 0; off >>= 1) part += __shfl_down(part, off);
    if (lane == 0) wsum[w] = part;
    __syncthreads();
    if (tid == 0) {
        float t = (wsum[0] + wsum[1] + wsum[2] + wsum[3]) * (1.25f / 4194304.f);
        atomicAdd(out + 4194304, t);
    }
}

// ================= launcher =================
extern "C" void kernel_launch(void* const* d_in, const int* in_sizes, int n_in,
                              void* d_out, int out_size, void* d_ws, size_t ws_size,
                              hipStream_t stream) {
    const float* z = (const float*)d_in[0];
    const float* cb = (const float*)d_in[1];
    float* out = (float*)d_out;
    char* wsb = (char*)d_ws;

    if (ws_size >= WS_NEED) {
        float* zn = (float*)(wsb + ZN_B);
        float* mrg = (float*)(wsb + MRG_B);
        unsigned* cnt = (unsigned*)(wsb + CNT_B);
        unsigned* tau_g = (unsigned*)(wsb + TAU_B);
        int* cand = (int*)(wsb + CAND_B);
        unsigned short* zh = (unsigned short*)(wsb + ZH_B);
        unsigned short* ch = (unsigned short*)(wsb + CH_B);

        hipMemsetAsync(wsb + CNT_B, 0, 131072, stream);   // cnt + tau (key 0)
        hipMemsetAsync(out + 4194304, 0, sizeof(float), stream);

        znorm_kernel<<<64, 256, 0, stream>>>(z, zn, mrg);
        split_z_kernel<<<dim3(16, 4, 16), 256, 0, stream>>>(z, zh);
        split_c_kernel<<<2048, 256, 0, stream>>>(cb, ch);
        gemm_screen32<<<256, 512, 0, stream>>>(zh, ch, mrg, tau_g, cnt, cand);
        select_finalize<<<256, 256, 0, stream>>>(z, cb, zn, cnt, cand, out);
    } else {
        float* zn = (float*)wsb;
        float* mrgdummy = (float*)(wsb + 65536);
        float* pscore = (float*)wsb + PSCORE_OFF;
        int* pidx = (int*)((float*)wsb + PIDX_OFF);
        znorm_kernel<<<64, 256, 0, stream>>>(z, zn, mrgdummy);
        dim3 grid(16384 / NT, KS);
        dist_argmin_kernel<<<grid, 256, 0, stream>>>(z, cb, zn, pscore, pidx);
        hipMemsetAsync(out + 4194304, 0, sizeof(float), stream);
        finalize_kernel<<<16384 / 64, 256, 0, stream>>>(z, cb, pscore, pidx, out);
    }
}